// Round 7
// baseline (428.470 us; speedup 1.0000x reference)
//
#include <hip/hip_runtime.h>
#include <hip/hip_bf16.h>
#include <stdint.h>

typedef __attribute__((ext_vector_type(8))) __bf16 bf16x8;
typedef __attribute__((ext_vector_type(4))) float f32x4;

#define GLOAD_LDS16(gp, lp) __builtin_amdgcn_global_load_lds( \
    (const __attribute__((address_space(1))) void*)(gp),      \
    (__attribute__((address_space(3))) void*)(lp), 16, 0, 0)

__device__ __forceinline__ uint16_t f2bf_rne(float f) {
  uint32_t u = __float_as_uint(f);
  u += 0x7FFFu + ((u >> 16) & 1u);
  return (uint16_t)(u >> 16);
}

// ---------------- fused f32 -> bf16 conversion (z, Wq, Wk in one launch) ----
__global__ __launch_bounds__(256) void cvt_all(
    const float* __restrict__ z, const float* __restrict__ wq,
    const float* __restrict__ wk, uint16_t* __restrict__ zb,
    uint16_t* __restrict__ wqb, uint16_t* __restrict__ wkb) {
  const int bid = blockIdx.x;
  const float* src;
  uint16_t* dst;
  int i;
  if (bid < 4096)        { src = z;  dst = zb;  i = bid * 256 + threadIdx.x; }
  else if (bid < 12288)  { src = wq; dst = wqb; i = (bid - 4096) * 256 + threadIdx.x; }
  else                   { src = wk; dst = wkb; i = (bid - 12288) * 256 + threadIdx.x; }
  const float4* s4 = (const float4*)src;
  float4 a = s4[2 * i], b = s4[2 * i + 1];
  union { uint16_t u[8]; uint4 v; } o;
  o.u[0] = f2bf_rne(a.x); o.u[1] = f2bf_rne(a.y);
  o.u[2] = f2bf_rne(a.z); o.u[3] = f2bf_rne(a.w);
  o.u[4] = f2bf_rne(b.x); o.u[5] = f2bf_rne(b.y);
  o.u[6] = f2bf_rne(b.z); o.u[7] = f2bf_rne(b.w);
  ((uint4*)dst)[i] = o.v;
}

// ---------------- bf16 GEMM, 256x256 tile, 16 waves ------------------------
// R7: B read DIRECT from global into registers (L1-served, 4-way wn-share),
// software-pipelined one K-tile ahead (bbA/bbB ping-pong, compiler-counted
// vmcnt). A keeps ring-4 LDS staging (16KB slots, XOR swizzle). LDS traffic
// halves; MFMA of kt depends only on regs from kt-1 -> reads overlap MFMA.
// Hazards: stage(kt) drained by HW-mandated bb(kt)-wait (issued after it);
// WAR on ring slot protected by one barrier/iter. vmcnt(6) is redundancy.
#define PH_BAR() do { asm volatile("" ::: "memory");            \
                      __builtin_amdgcn_s_barrier();             \
                      asm volatile("" ::: "memory"); } while (0)

#define STEP(kt, BBC, BBN, DO_STAGE, DO_BB)                                    \
  do {                                                                         \
    const char* Ab_ = lds + ((kt) & 3) * 16384;                                \
    bf16x8 aa[4];                                                              \
    _Pragma("unroll")                                                          \
    for (int m_ = 0; m_ < 4; ++m_)                                             \
      aa[m_] = *(const bf16x8*)(Ab_ + aoff + m_ * 1024);                       \
    if (DO_BB) {                                                               \
      _Pragma("unroll")                                                        \
      for (int n_ = 0; n_ < 4; ++n_)                                           \
        BBN[n_] = *(const bf16x8*)(bbase + (size_t)n_ * 65536 +                \
                                   ((kt) + 1) * 32);                           \
    }                                                                          \
    if (DO_STAGE)                                                              \
      GLOAD_LDS16(aptr + (size_t)((kt) + 3) * 32,                              \
                  lds + (((kt) + 3) & 3) * 16384 + t16);                       \
    __builtin_amdgcn_s_setprio(1);                                             \
    _Pragma("unroll")                                                          \
    for (int m_ = 0; m_ < 4; ++m_)                                             \
      _Pragma("unroll")                                                        \
      for (int n_ = 0; n_ < 4; ++n_)                                           \
        acc[m_][n_] = __builtin_amdgcn_mfma_f32_16x16x32_bf16(                 \
            aa[m_], BBC[n_], acc[m_][n_], 0, 0, 0);                            \
    __builtin_amdgcn_s_setprio(0);                                             \
    asm volatile("s_waitcnt vmcnt(6)" ::: "memory");                           \
    PH_BAR();                                                                  \
  } while (0)

__global__ __launch_bounds__(1024, 4) void gemm_qk16(
    const uint16_t* __restrict__ A,
    const uint16_t* __restrict__ Bq, const uint16_t* __restrict__ Bk,
    uint16_t* __restrict__ Cq, uint16_t* __restrict__ Ck) {
  extern __shared__ char lds[];  // 65536 bytes: 4 ring slots x A 16K

  // bijective supertile: xcd = gid&7 -> (tm half, tn quarter); 32 blocks/XCD
  const int gid = blockIdx.x;
  const int xcd = gid & 7;
  const int idx = gid >> 3;          // 0..31
  const int which = idx & 1;
  const int r = idx >> 1;            // 0..15
  const int tm = (xcd & 1) * 4 + (r & 3);
  const int tn = (xcd >> 1) * 4 + (r >> 2);

  const uint16_t* Bmat = which ? Bk : Bq;
  uint16_t* C = which ? Ck : Cq;
  const int m0 = tm * 256, n0 = tn * 256;

  const int t = threadIdx.x;
  const int lane = t & 63;
  const int w = t >> 6;              // 0..15
  const int wm = w >> 2, wn = w & 3; // 4x4 wave grid, each 64x64 output
  const int t16 = t * 16;

  // A staging: thread t covers row t>>2, k-granule t&3 (pre-swizzled source)
  const int gsw = (((t & 3) ^ ((t >> 3) & 3)) * 8);
  const uint16_t* aptr = A + (size_t)(m0 + (t >> 2)) * 4096 + gsw;

  // A ds_read byte offsets (same XOR involution on the read side)
  const int sl = ((lane >> 4) ^ ((lane & 15) >> 1)) & 3;
  const int aoff = (wm * 64 + (lane & 15)) * 64 + sl * 16;

  // B direct-global fragment base: col = n0+wn*64+n_*16+(lane&15),
  // k = kt*32 + (lane>>4)*8   (16B aligned loads, 64B segments per 16 lanes)
  const uint16_t* bbase =
      Bmat + (size_t)(n0 + wn * 64 + (lane & 15)) * 4096 + ((lane >> 4) * 8);

  f32x4 acc[4][4] = {};
  bf16x8 bbA[4], bbB[4];

  // prologue: bb(0) -> bbA; stage K-tiles 0,1,2; wait stage(0) (2 newer left)
#pragma unroll
  for (int n_ = 0; n_ < 4; ++n_)
    bbA[n_] = *(const bf16x8*)(bbase + (size_t)n_ * 65536);
#pragma unroll
  for (int p = 0; p < 3; ++p)
    GLOAD_LDS16(aptr + (size_t)p * 32, lds + p * 16384 + t16);
  asm volatile("s_waitcnt vmcnt(2)" ::: "memory");
  PH_BAR();

  for (int kt = 0; kt < 124; kt += 2) {
    STEP(kt,     bbA, bbB, 1, 1);
    STEP(kt + 1, bbB, bbA, 1, 1);
  }
  STEP(124, bbA, bbB, 1, 1);   // stages tile 127 (last)
  STEP(125, bbB, bbA, 0, 1);
  STEP(126, bbA, bbB, 0, 1);
  STEP(127, bbB, bbA, 0, 0);

  // epilogue: C/D layout col=lane&15, row=(lane>>4)*4+j ; store bf16
  const int colb = n0 + wn * 64 + (lane & 15);
  const int rowb = m0 + wm * 64 + (lane >> 4) * 4;
#pragma unroll
  for (int m_ = 0; m_ < 4; ++m_)
#pragma unroll
    for (int n_ = 0; n_ < 4; ++n_)
#pragma unroll
      for (int j = 0; j < 4; ++j)
        C[(size_t)(rowb + m_ * 16 + j) * 4096 + colb + n_ * 16] =
            f2bf_rne(acc[m_][n_][j]);
}

// ---------------- MFMA scores + softmax -> attn[256][64][64] f32 ------------
// Per head n: Qh = Qb[n*32768 ..] is [512 d][64 i] bf16 (i-fastest).
// scores[i,j] = (1/sqrt(512)) sum_d Qh[d][i] Kh[d][j].
// LDS chunk [64 th][64 i], granule rotation rot(th) = (th + 2*(th>>3)) & 7.
__device__ __forceinline__ bf16x8 load_frag_rot(const uint16_t* buf,
                                                int ij, int thb) {
  union { uint16_t u[8]; bf16x8 v; } r;
#pragma unroll
  for (int e = 0; e < 8; ++e) {
    const int th = thb + e;
    const int rot = (th + 2 * (th >> 3)) & 7;
    const int irot = (ij + rot * 8) & 63;
    r.u[e] = buf[th * 64 + irot];
  }
  return r.v;
}

__global__ __launch_bounds__(256) void attn_scores_mfma(
    const uint16_t* __restrict__ Qb, const uint16_t* __restrict__ Kb,
    float* __restrict__ attn) {
  const int n = blockIdx.x;
  __shared__ uint16_t q_l[2][4096];
  __shared__ uint16_t k_l[2][4096];
  __shared__ float scores_l[64 * 68];

  const int t = threadIdx.x;
  const int lane = t & 63;
  const int w = t >> 6;
  const int i0w = (w >> 1) * 32, j0w = (w & 1) * 32;

  const uint16_t* Qn = Qb + (size_t)n * 32768;
  const uint16_t* Kn = Kb + (size_t)n * 32768;

  const int g1 = t, g2 = t + 256;
  const int th1 = g1 >> 3, th2 = g2 >> 3;
  const int s1 = (((g1 & 7) - ((th1 + 2 * (th1 >> 3)) & 7)) & 7);
  const int s2 = (((g2 & 7) - ((th2 + 2 * (th2 >> 3)) & 7)) & 7);
  const size_t so1 = (size_t)th1 * 64 + s1 * 8;
  const size_t so2 = (size_t)th2 * 64 + s2 * 8;

#define STAGE_CH(bf, cm)                                                    \
  do {                                                                      \
    const size_t co_ = (size_t)(cm) * 4096;                                 \
    GLOAD_LDS16(Qn + co_ + so1, (char*)&q_l[bf][0] + g1 * 16);              \
    GLOAD_LDS16(Qn + co_ + so2, (char*)&q_l[bf][0] + g2 * 16);              \
    GLOAD_LDS16(Kn + co_ + so1, (char*)&k_l[bf][0] + g1 * 16);              \
    GLOAD_LDS16(Kn + co_ + so2, (char*)&k_l[bf][0] + g2 * 16);              \
  } while (0)

  f32x4 acc[2][2] = {};

  STAGE_CH(0, 0);
  asm volatile("s_waitcnt vmcnt(0)" ::: "memory");
  __syncthreads();

  for (int cm = 0; cm < 8; ++cm) {
    const int bf = cm & 1;
    if (cm < 7) STAGE_CH(bf ^ 1, cm + 1);
#pragma unroll
    for (int ks = 0; ks < 2; ++ks) {
      const int thb = ks * 32 + (lane >> 4) * 8;
      bf16x8 aa0 = load_frag_rot(&q_l[bf][0], i0w + (lane & 15), thb);
      bf16x8 aa1 = load_frag_rot(&q_l[bf][0], i0w + 16 + (lane & 15), thb);
      bf16x8 bb0 = load_frag_rot(&k_l[bf][0], j0w + (lane & 15), thb);
      bf16x8 bb1 = load_frag_rot(&k_l[bf][0], j0w + 16 + (lane & 15), thb);
      acc[0][0] = __builtin_amdgcn_mfma_f32_16x16x32_bf16(aa0, bb0, acc[0][0], 0, 0, 0);
      acc[0][1] = __builtin_amdgcn_mfma_f32_16x16x32_bf16(aa0, bb1, acc[0][1], 0, 0, 0);
      acc[1][0] = __builtin_amdgcn_mfma_f32_16x16x32_bf16(aa1, bb0, acc[1][0], 0, 0, 0);
      acc[1][1] = __builtin_amdgcn_mfma_f32_16x16x32_bf16(aa1, bb1, acc[1][1], 0, 0, 0);
    }
    asm volatile("s_waitcnt vmcnt(0)" ::: "memory");
    __syncthreads();
  }
#undef STAGE_CH

#pragma unroll
  for (int fi = 0; fi < 2; ++fi)
#pragma unroll
    for (int fj = 0; fj < 2; ++fj)
#pragma unroll
      for (int jr = 0; jr < 4; ++jr) {
        const int i = i0w + fi * 16 + (lane >> 4) * 4 + jr;
        const int j = j0w + fj * 16 + (lane & 15);
        scores_l[i * 68 + j] = acc[fi][fj][jr];
      }
  __syncthreads();

  {
    const int i = t >> 2, jg = t & 3;
    float pv[16];
    *(float4*)(pv + 0)  = *(const float4*)&scores_l[i * 68 + jg * 16 + 0];
    *(float4*)(pv + 4)  = *(const float4*)&scores_l[i * 68 + jg * 16 + 4];
    *(float4*)(pv + 8)  = *(const float4*)&scores_l[i * 68 + jg * 16 + 8];
    *(float4*)(pv + 12) = *(const float4*)&scores_l[i * 68 + jg * 16 + 12];
    float m = pv[0];
#pragma unroll
    for (int q = 1; q < 16; ++q) m = fmaxf(m, pv[q]);
    m = fmaxf(m, __shfl_xor(m, 1, 64));
    m = fmaxf(m, __shfl_xor(m, 2, 64));
    const float sc = 0.044194173824159216f * 1.4426950408889634f;
    float e[16];
    float ssum = 0.f;
#pragma unroll
    for (int q = 0; q < 16; ++q) {
      e[q] = exp2f((pv[q] - m) * sc);
      ssum += e[q];
    }
    ssum += __shfl_xor(ssum, 1, 64);
    ssum += __shfl_xor(ssum, 2, 64);
    const float inv = 1.0f / ssum;
    float ov[16];
#pragma unroll
    for (int q = 0; q < 16; ++q) ov[q] = e[q] * inv;
    float* dst = attn + (size_t)n * 4096 + i * 64 + jg * 16;
    *(float4*)(dst + 0)  = *(float4*)(ov + 0);
    *(float4*)(dst + 4)  = *(float4*)(ov + 4);
    *(float4*)(dst + 8)  = *(float4*)(ov + 8);
    *(float4*)(dst + 12) = *(float4*)(ov + 12);
  }
}

// ---------------- V = x-slab * Wv^T ; context = V @ attn ; leaky; scatter ----
__global__ __launch_bounds__(256) void ctx_kernel(
    const float* __restrict__ x, const float* __restrict__ Wv,
    const float* __restrict__ attn, float* __restrict__ out) {
  const int n = blockIdx.x >> 3, ut = blockIdx.x & 7;
  const int b = n >> 3, g = n & 7;
  const int u0 = ut * 64;
  __shared__ float attn_l[64 * 64];
  __shared__ float wv_l[64 * 64];
  __shared__ float x_l[64 * 64];
  __shared__ float v_l[64 * 64];
  const int t = threadIdx.x;

#pragma unroll
  for (int r = 0; r < 4; ++r) {
    ((float4*)attn_l)[r * 256 + t] =
        ((const float4*)(attn + (size_t)n * 4096))[r * 256 + t];
    ((float4*)wv_l)[r * 256 + t] = ((const float4*)Wv)[r * 256 + t];
  }
  {
    const float* xbase = x + (size_t)b * 262144 + (size_t)g * 512 + u0;
    const int ul4 = (t & 15) * 4;
    const int cc0 = t >> 4;
#pragma unroll
    for (int r = 0; r < 4; ++r) {
      int cc = cc0 + r * 16;
      *(float4*)&x_l[cc * 64 + ul4] = *(const float4*)&xbase[(size_t)cc * 4096 + ul4];
    }
  }
  __syncthreads();
  {
    const int ul = t & 63, e0 = t >> 6;
    float vacc[16];
#pragma unroll
    for (int ee = 0; ee < 16; ++ee) vacc[ee] = 0.f;
    for (int cc = 0; cc < 64; ++cc) {
      float xv = x_l[cc * 64 + ul];
#pragma unroll
      for (int ee = 0; ee < 16; ++ee)
        vacc[ee] += xv * wv_l[(e0 + 4 * ee) * 64 + cc];
    }
#pragma unroll
    for (int ee = 0; ee < 16; ++ee) v_l[(e0 + 4 * ee) * 64 + ul] = vacc[ee];
  }
  __syncthreads();
  {
    const int ul = t & 63, j0 = t >> 6;
    float cacc[16];
#pragma unroll
    for (int jj = 0; jj < 16; ++jj) cacc[jj] = 0.f;
    for (int c = 0; c < 64; ++c) {
      float vv = v_l[c * 64 + ul];
#pragma unroll
      for (int jj = 0; jj < 16; ++jj)
        cacc[jj] += vv * attn_l[c * 64 + j0 + 4 * jj];
    }
    float* ob = out + (size_t)b * 262144 + (size_t)g * 8 * 4096;
#pragma unroll
    for (int jj = 0; jj < 16; ++jj) {
      int j = j0 + 4 * jj;
      float v = cacc[jj];
      v = v > 0.f ? v : 0.2f * v;
      ob[(size_t)(j >> 3) * 4096 + (size_t)(j & 7) * 512 + u0 + ul] = v;
    }
  }
}

extern "C" void kernel_launch(void* const* d_in, const int* in_sizes, int n_in,
                              void* d_out, int out_size, void* d_ws, size_t ws_size,
                              hipStream_t stream) {
  const float* z  = (const float*)d_in[0];
  const float* x  = (const float*)d_in[1];
  const float* Wq = (const float*)d_in[2];
  const float* Wk = (const float*)d_in[3];
  const float* Wv = (const float*)d_in[4];
  float* out = (float*)d_out;

  char* ws = (char*)d_ws;
  uint16_t* zb   = (uint16_t*)(ws);                  // 16 MB
  uint16_t* wqb  = (uint16_t*)(ws + 16777216);       // 32 MB
  uint16_t* wkb  = (uint16_t*)(ws + 50331648);       // 32 MB
  uint16_t* qbo  = (uint16_t*)(ws + 83886080);       // 16 MB bf16 Q
  uint16_t* kbo  = (uint16_t*)(ws + 100663296);      // 16 MB bf16 K
  float*    attn = (float*)(ws + 117440512);         // 4 MB f32

  cvt_all<<<20480, 256, 0, stream>>>(z, Wq, Wk, zb, wqb, wkb);

  (void)hipFuncSetAttribute((const void*)gemm_qk16,
                            hipFuncAttributeMaxDynamicSharedMemorySize, 65536);
  gemm_qk16<<<256, 1024, 65536, stream>>>(zb, wqb, wkb, qbo, kbo);

  attn_scores_mfma<<<256, 256, 0, stream>>>(qbo, kbo, attn);
  ctx_kernel<<<2048, 256, 0, stream>>>(x, Wv, attn, out);
}

// Round 8
// 241.928 us; speedup vs baseline: 1.7711x; 1.7711x over previous
//
#include <hip/hip_runtime.h>
#include <hip/hip_bf16.h>
#include <stdint.h>

typedef __attribute__((ext_vector_type(8))) __bf16 bf16x8;
typedef __attribute__((ext_vector_type(4))) float f32x4;

#define GLOAD_LDS16(gp, lp) __builtin_amdgcn_global_load_lds( \
    (const __attribute__((address_space(1))) void*)(gp),      \
    (__attribute__((address_space(3))) void*)(lp), 16, 0, 0)

__device__ __forceinline__ uint16_t f2bf_rne(float f) {
  uint32_t u = __float_as_uint(f);
  u += 0x7FFFu + ((u >> 16) & 1u);
  return (uint16_t)(u >> 16);
}

// ---------------- fused f32 -> bf16 conversion (z, Wq, Wk in one launch) ----
__global__ __launch_bounds__(256) void cvt_all(
    const float* __restrict__ z, const float* __restrict__ wq,
    const float* __restrict__ wk, uint16_t* __restrict__ zb,
    uint16_t* __restrict__ wqb, uint16_t* __restrict__ wkb) {
  const int bid = blockIdx.x;
  const float* src;
  uint16_t* dst;
  int i;
  if (bid < 4096)        { src = z;  dst = zb;  i = bid * 256 + threadIdx.x; }
  else if (bid < 12288)  { src = wq; dst = wqb; i = (bid - 4096) * 256 + threadIdx.x; }
  else                   { src = wk; dst = wkb; i = (bid - 12288) * 256 + threadIdx.x; }
  const float4* s4 = (const float4*)src;
  float4 a = s4[2 * i], b = s4[2 * i + 1];
  union { uint16_t u[8]; uint4 v; } o;
  o.u[0] = f2bf_rne(a.x); o.u[1] = f2bf_rne(a.y);
  o.u[2] = f2bf_rne(a.z); o.u[3] = f2bf_rne(a.w);
  o.u[4] = f2bf_rne(b.x); o.u[5] = f2bf_rne(b.y);
  o.u[6] = f2bf_rne(b.z); o.u[7] = f2bf_rne(b.w);
  ((uint4*)dst)[i] = o.v;
}

// ---------------- bf16 GEMM, 256x256 tile, 16 waves, ring-4 BK=32 -----------
// R8: R6 dataflow (A+B LDS ring-4, XOR swizzle, bijective XCD supertile,
// one barrier/K-tile) + register prefetch of NEXT tile's A-fragments
// (aaA/aaB ping-pong) so 8 of 12 ds_reads/wave overlap the MFMA phase.
// vmcnt(2): stage(kt+1) AND (kt+2) must be complete at barrier(kt) since
// iter kt+1 reads A from slot kt+2; stage(kt+3) stays in flight.
#define PH_BAR() do { asm volatile("" ::: "memory");            \
                      __builtin_amdgcn_s_barrier();             \
                      asm volatile("" ::: "memory"); } while (0)

#define STEP(kt, AAC, AAN, DO_PREF, DO_STAGE)                                  \
  do {                                                                         \
    const char* Ab_ = lds + ((kt) & 3) * 32768;                                \
    bf16x8 bb[4];                                                              \
    _Pragma("unroll")                                                          \
    for (int n_ = 0; n_ < 4; ++n_)                                             \
      bb[n_] = *(const bf16x8*)(Ab_ + 16384 + boff + n_ * 1024);               \
    if (DO_PREF) {                                                             \
      const char* An_ = lds + (((kt) + 1) & 3) * 32768;                        \
      _Pragma("unroll")                                                        \
      for (int m_ = 0; m_ < 4; ++m_)                                           \
        AAN[m_] = *(const bf16x8*)(An_ + aoff + m_ * 1024);                    \
    }                                                                          \
    if (DO_STAGE) {                                                            \
      const int ss_ = ((kt) + 3) & 3;                                          \
      GLOAD_LDS16(aptr + (size_t)((kt) + 3) * 32, lds + ss_ * 32768 + t16);    \
      GLOAD_LDS16(bptr + (size_t)((kt) + 3) * 32,                              \
                  lds + ss_ * 32768 + 16384 + t16);                            \
    }                                                                          \
    __builtin_amdgcn_s_setprio(1);                                             \
    _Pragma("unroll")                                                          \
    for (int m_ = 0; m_ < 4; ++m_)                                             \
      _Pragma("unroll")                                                        \
      for (int n_ = 0; n_ < 4; ++n_)                                           \
        acc[m_][n_] = __builtin_amdgcn_mfma_f32_16x16x32_bf16(                 \
            AAC[m_], bb[n_], acc[m_][n_], 0, 0, 0);                            \
    __builtin_amdgcn_s_setprio(0);                                             \
  } while (0)

__global__ __launch_bounds__(1024, 4) void gemm_qk16(
    const uint16_t* __restrict__ A,
    const uint16_t* __restrict__ Bq, const uint16_t* __restrict__ Bk,
    uint16_t* __restrict__ Cq, uint16_t* __restrict__ Ck) {
  extern __shared__ char lds[];  // 131072: 4 ring slots x (A 16K + B 16K)

  // bijective supertile: xcd = gid&7 -> (tm half, tn quarter); 32 blocks/XCD
  const int gid = blockIdx.x;
  const int xcd = gid & 7;
  const int idx = gid >> 3;          // 0..31
  const int which = idx & 1;
  const int r = idx >> 1;            // 0..15
  const int tm = (xcd & 1) * 4 + (r & 3);
  const int tn = (xcd >> 1) * 4 + (r >> 2);

  const uint16_t* Bmat = which ? Bk : Bq;
  uint16_t* C = which ? Ck : Cq;
  const int m0 = tm * 256, n0 = tn * 256;

  const int t = threadIdx.x;
  const int lane = t & 63;
  const int w = t >> 6;              // 0..15
  const int wm = w >> 2, wn = w & 3; // 4x4 wave grid, each 64x64 output
  const int t16 = t * 16;

  // staging: thread t covers row t>>2, k-granule t&3 (pre-swizzled source)
  const int gsw = (((t & 3) ^ ((t >> 3) & 3)) * 8);
  const uint16_t* aptr = A    + (size_t)(m0 + (t >> 2)) * 4096 + gsw;
  const uint16_t* bptr = Bmat + (size_t)(n0 + (t >> 2)) * 4096 + gsw;

  // ds_read byte offsets (same XOR involution on the read side)
  const int sl = ((lane >> 4) ^ ((lane & 15) >> 1)) & 3;
  const int aoff = (wm * 64 + (lane & 15)) * 64 + sl * 16;
  const int boff = (wn * 64 + (lane & 15)) * 64 + sl * 16;

  f32x4 acc[4][4] = {};
  bf16x8 aaA[4], aaB[4];

  // prologue: stage K-tiles 0,1,2; slots 0 AND 1 must be ready (iter 0 reads
  // bb slot0 + prefetches aa slot1) -> vmcnt(2); then pre-read aaA = A slot0.
#pragma unroll
  for (int p = 0; p < 3; ++p) {
    GLOAD_LDS16(aptr + (size_t)p * 32, lds + p * 32768 + t16);
    GLOAD_LDS16(bptr + (size_t)p * 32, lds + p * 32768 + 16384 + t16);
  }
  asm volatile("s_waitcnt vmcnt(2)" ::: "memory");
  PH_BAR();
#pragma unroll
  for (int m_ = 0; m_ < 4; ++m_)
    aaA[m_] = *(const bf16x8*)(lds + aoff + m_ * 1024);

  for (int kt = 0; kt < 124; kt += 2) {
    STEP(kt, aaA, aaB, 1, 1);
    asm volatile("s_waitcnt vmcnt(2)" ::: "memory");
    PH_BAR();
    STEP(kt + 1, aaB, aaA, 1, 1);
    asm volatile("s_waitcnt vmcnt(2)" ::: "memory");
    PH_BAR();
  }
  STEP(124, aaA, aaB, 1, 1);   // stages slot 127 (last)
  asm volatile("s_waitcnt vmcnt(2)" ::: "memory");
  PH_BAR();
  STEP(125, aaB, aaA, 1, 0);
  asm volatile("s_waitcnt vmcnt(0)" ::: "memory");
  PH_BAR();
  STEP(126, aaA, aaB, 1, 0);
  PH_BAR();
  STEP(127, aaB, aaA, 0, 0);

  // epilogue: C/D layout col=lane&15, row=(lane>>4)*4+j ; store bf16
  const int colb = n0 + wn * 64 + (lane & 15);
  const int rowb = m0 + wm * 64 + (lane >> 4) * 4;
#pragma unroll
  for (int m_ = 0; m_ < 4; ++m_)
#pragma unroll
    for (int n_ = 0; n_ < 4; ++n_)
#pragma unroll
      for (int j = 0; j < 4; ++j)
        C[(size_t)(rowb + m_ * 16 + j) * 4096 + colb + n_ * 16] =
            f2bf_rne(acc[m_][n_][j]);
}

// ---------------- MFMA scores + softmax -> attn[256][64][64] f32 ------------
__device__ __forceinline__ bf16x8 load_frag_rot(const uint16_t* buf,
                                                int ij, int thb) {
  union { uint16_t u[8]; bf16x8 v; } r;
#pragma unroll
  for (int e = 0; e < 8; ++e) {
    const int th = thb + e;
    const int rot = (th + 2 * (th >> 3)) & 7;
    const int irot = (ij + rot * 8) & 63;
    r.u[e] = buf[th * 64 + irot];
  }
  return r.v;
}

__global__ __launch_bounds__(256) void attn_scores_mfma(
    const uint16_t* __restrict__ Qb, const uint16_t* __restrict__ Kb,
    float* __restrict__ attn) {
  const int n = blockIdx.x;
  __shared__ uint16_t q_l[2][4096];
  __shared__ uint16_t k_l[2][4096];
  __shared__ float scores_l[64 * 68];

  const int t = threadIdx.x;
  const int lane = t & 63;
  const int w = t >> 6;
  const int i0w = (w >> 1) * 32, j0w = (w & 1) * 32;

  const uint16_t* Qn = Qb + (size_t)n * 32768;
  const uint16_t* Kn = Kb + (size_t)n * 32768;

  const int g1 = t, g2 = t + 256;
  const int th1 = g1 >> 3, th2 = g2 >> 3;
  const int s1 = (((g1 & 7) - ((th1 + 2 * (th1 >> 3)) & 7)) & 7);
  const int s2 = (((g2 & 7) - ((th2 + 2 * (th2 >> 3)) & 7)) & 7);
  const size_t so1 = (size_t)th1 * 64 + s1 * 8;
  const size_t so2 = (size_t)th2 * 64 + s2 * 8;

#define STAGE_CH(bf, cm)                                                    \
  do {                                                                      \
    const size_t co_ = (size_t)(cm) * 4096;                                 \
    GLOAD_LDS16(Qn + co_ + so1, (char*)&q_l[bf][0] + g1 * 16);              \
    GLOAD_LDS16(Qn + co_ + so2, (char*)&q_l[bf][0] + g2 * 16);              \
    GLOAD_LDS16(Kn + co_ + so1, (char*)&k_l[bf][0] + g1 * 16);              \
    GLOAD_LDS16(Kn + co_ + so2, (char*)&k_l[bf][0] + g2 * 16);              \
  } while (0)

  f32x4 acc[2][2] = {};

  STAGE_CH(0, 0);
  asm volatile("s_waitcnt vmcnt(0)" ::: "memory");
  __syncthreads();

  for (int cm = 0; cm < 8; ++cm) {
    const int bf = cm & 1;
    if (cm < 7) STAGE_CH(bf ^ 1, cm + 1);
#pragma unroll
    for (int ks = 0; ks < 2; ++ks) {
      const int thb = ks * 32 + (lane >> 4) * 8;
      bf16x8 aa0 = load_frag_rot(&q_l[bf][0], i0w + (lane & 15), thb);
      bf16x8 aa1 = load_frag_rot(&q_l[bf][0], i0w + 16 + (lane & 15), thb);
      bf16x8 bb0 = load_frag_rot(&k_l[bf][0], j0w + (lane & 15), thb);
      bf16x8 bb1 = load_frag_rot(&k_l[bf][0], j0w + 16 + (lane & 15), thb);
      acc[0][0] = __builtin_amdgcn_mfma_f32_16x16x32_bf16(aa0, bb0, acc[0][0], 0, 0, 0);
      acc[0][1] = __builtin_amdgcn_mfma_f32_16x16x32_bf16(aa0, bb1, acc[0][1], 0, 0, 0);
      acc[1][0] = __builtin_amdgcn_mfma_f32_16x16x32_bf16(aa1, bb0, acc[1][0], 0, 0, 0);
      acc[1][1] = __builtin_amdgcn_mfma_f32_16x16x32_bf16(aa1, bb1, acc[1][1], 0, 0, 0);
    }
    asm volatile("s_waitcnt vmcnt(0)" ::: "memory");
    __syncthreads();
  }
#undef STAGE_CH

#pragma unroll
  for (int fi = 0; fi < 2; ++fi)
#pragma unroll
    for (int fj = 0; fj < 2; ++fj)
#pragma unroll
      for (int jr = 0; jr < 4; ++jr) {
        const int i = i0w + fi * 16 + (lane >> 4) * 4 + jr;
        const int j = j0w + fj * 16 + (lane & 15);
        scores_l[i * 68 + j] = acc[fi][fj][jr];
      }
  __syncthreads();

  {
    const int i = t >> 2, jg = t & 3;
    float pv[16];
    *(float4*)(pv + 0)  = *(const float4*)&scores_l[i * 68 + jg * 16 + 0];
    *(float4*)(pv + 4)  = *(const float4*)&scores_l[i * 68 + jg * 16 + 4];
    *(float4*)(pv + 8)  = *(const float4*)&scores_l[i * 68 + jg * 16 + 8];
    *(float4*)(pv + 12) = *(const float4*)&scores_l[i * 68 + jg * 16 + 12];
    float m = pv[0];
#pragma unroll
    for (int q = 1; q < 16; ++q) m = fmaxf(m, pv[q]);
    m = fmaxf(m, __shfl_xor(m, 1, 64));
    m = fmaxf(m, __shfl_xor(m, 2, 64));
    const float sc = 0.044194173824159216f * 1.4426950408889634f;
    float e[16];
    float ssum = 0.f;
#pragma unroll
    for (int q = 0; q < 16; ++q) {
      e[q] = exp2f((pv[q] - m) * sc);
      ssum += e[q];
    }
    ssum += __shfl_xor(ssum, 1, 64);
    ssum += __shfl_xor(ssum, 2, 64);
    const float inv = 1.0f / ssum;
    float ov[16];
#pragma unroll
    for (int q = 0; q < 16; ++q) ov[q] = e[q] * inv;
    float* dst = attn + (size_t)n * 4096 + i * 64 + jg * 16;
    *(float4*)(dst + 0)  = *(float4*)(ov + 0);
    *(float4*)(dst + 4)  = *(float4*)(ov + 4);
    *(float4*)(dst + 8)  = *(float4*)(ov + 8);
    *(float4*)(dst + 12) = *(float4*)(ov + 12);
  }
}

// ---------------- V = x-slab * Wv^T ; context = V @ attn ; leaky; scatter ----
__global__ __launch_bounds__(256) void ctx_kernel(
    const float* __restrict__ x, const float* __restrict__ Wv,
    const float* __restrict__ attn, float* __restrict__ out) {
  const int n = blockIdx.x >> 3, ut = blockIdx.x & 7;
  const int b = n >> 3, g = n & 7;
  const int u0 = ut * 64;
  __shared__ float attn_l[64 * 64];
  __shared__ float wv_l[64 * 64];
  __shared__ float x_l[64 * 64];
  __shared__ float v_l[64 * 64];
  const int t = threadIdx.x;

#pragma unroll
  for (int r = 0; r < 4; ++r) {
    ((float4*)attn_l)[r * 256 + t] =
        ((const float4*)(attn + (size_t)n * 4096))[r * 256 + t];
    ((float4*)wv_l)[r * 256 + t] = ((const float4*)Wv)[r * 256 + t];
  }
  {
    const float* xbase = x + (size_t)b * 262144 + (size_t)g * 512 + u0;
    const int ul4 = (t & 15) * 4;
    const int cc0 = t >> 4;
#pragma unroll
    for (int r = 0; r < 4; ++r) {
      int cc = cc0 + r * 16;
      *(float4*)&x_l[cc * 64 + ul4] = *(const float4*)&xbase[(size_t)cc * 4096 + ul4];
    }
  }
  __syncthreads();
  {
    const int ul = t & 63, e0 = t >> 6;
    float vacc[16];
#pragma unroll
    for (int ee = 0; ee < 16; ++ee) vacc[ee] = 0.f;
    for (int cc = 0; cc < 64; ++cc) {
      float xv = x_l[cc * 64 + ul];
#pragma unroll
      for (int ee = 0; ee < 16; ++ee)
        vacc[ee] += xv * wv_l[(e0 + 4 * ee) * 64 + cc];
    }
#pragma unroll
    for (int ee = 0; ee < 16; ++ee) v_l[(e0 + 4 * ee) * 64 + ul] = vacc[ee];
  }
  __syncthreads();
  {
    const int ul = t & 63, j0 = t >> 6;
    float cacc[16];
#pragma unroll
    for (int jj = 0; jj < 16; ++jj) cacc[jj] = 0.f;
    for (int c = 0; c < 64; ++c) {
      float vv = v_l[c * 64 + ul];
#pragma unroll
      for (int jj = 0; jj < 16; ++jj)
        cacc[jj] += vv * attn_l[c * 64 + j0 + 4 * jj];
    }
    float* ob = out + (size_t)b * 262144 + (size_t)g * 8 * 4096;
#pragma unroll
    for (int jj = 0; jj < 16; ++jj) {
      int j = j0 + 4 * jj;
      float v = cacc[jj];
      v = v > 0.f ? v : 0.2f * v;
      ob[(size_t)(j >> 3) * 4096 + (size_t)(j & 7) * 512 + u0 + ul] = v;
    }
  }
}

extern "C" void kernel_launch(void* const* d_in, const int* in_sizes, int n_in,
                              void* d_out, int out_size, void* d_ws, size_t ws_size,
                              hipStream_t stream) {
  const float* z  = (const float*)d_in[0];
  const float* x  = (const float*)d_in[1];
  const float* Wq = (const float*)d_in[2];
  const float* Wk = (const float*)d_in[3];
  const float* Wv = (const float*)d_in[4];
  float* out = (float*)d_out;

  char* ws = (char*)d_ws;
  uint16_t* zb   = (uint16_t*)(ws);                  // 16 MB
  uint16_t* wqb  = (uint16_t*)(ws + 16777216);       // 32 MB
  uint16_t* wkb  = (uint16_t*)(ws + 50331648);       // 32 MB
  uint16_t* qbo  = (uint16_t*)(ws + 83886080);       // 16 MB bf16 Q
  uint16_t* kbo  = (uint16_t*)(ws + 100663296);      // 16 MB bf16 K
  float*    attn = (float*)(ws + 117440512);         // 4 MB f32

  cvt_all<<<20480, 256, 0, stream>>>(z, Wq, Wk, zb, wqb, wkb);

  (void)hipFuncSetAttribute((const void*)gemm_qk16,
                            hipFuncAttributeMaxDynamicSharedMemorySize, 131072);
  gemm_qk16<<<256, 1024, 131072, stream>>>(zb, wqb, wkb, qbo, kbo);

  attn_scores_mfma<<<256, 256, 0, stream>>>(qbo, kbo, attn);
  ctx_kernel<<<2048, 256, 0, stream>>>(x, Wv, attn, out);
}